// Round 3
// baseline (22686.386 us; speedup 1.0000x reference)
//
#include <hip/hip_runtime.h>
#include <cstdint>

#define DEVI __device__ __forceinline__

typedef __bf16 bf16x8 __attribute__((ext_vector_type(8)));
typedef float f32x4 __attribute__((ext_vector_type(4)));

DEVI unsigned short f2b(float f) {
    unsigned int u = __builtin_bit_cast(unsigned int, f);
    unsigned int r = (u + 0x7FFFu + ((u >> 16) & 1u)) >> 16;
    return (unsigned short)r;
}
DEVI float frcp(float x) { return __builtin_amdgcn_rcpf(x); }
DEVI float sigm(float x) { return frcp(1.0f + __expf(-x)); }
DEVI float tanh_f(float x) {
    float e = __expf(-2.0f * fabsf(x));
    float r = (1.0f - e) * frcp(1.0f + e);
    return x < 0.0f ? -r : r;
}

// async global->LDS, 16B per lane; LDS dest wave-uniform base (HW adds lane*16).
DEVI void gload_lds16(const unsigned short* g, unsigned short* l) {
    typedef __attribute__((address_space(1))) void gv_t;
    typedef __attribute__((address_space(3))) void lv_t;
    gv_t* gp = (gv_t*)(uintptr_t)g;
    lv_t* lp = (lv_t*)(unsigned int)(uintptr_t)l;
    __builtin_amdgcn_global_load_lds(gp, lp, 16, 0, 0);
}

// ---------------- input transpose: (B,C,L) f32 -> xT (L+2, B, C) bf16, zero rows 0 and 129
__global__ void k_tin(const float* __restrict__ in, unsigned short* __restrict__ xT) {
    __shared__ float tile[32][33];
    int c0 = blockIdx.x * 32, t0 = blockIdx.y * 32, b = blockIdx.z;
    int tx = threadIdx.x, ty = threadIdx.y;
#pragma unroll
    for (int i = 0; i < 4; ++i) {
        int c = c0 + ty + i * 8;
        int t = t0 + tx;
        float v = 0.0f;
        if (t >= 1 && t <= 128) v = in[((size_t)b * 256 + c) * 128 + (t - 1)];
        tile[ty + i * 8][tx] = v;  // [c_local][t_local]
    }
    __syncthreads();
#pragma unroll
    for (int i = 0; i < 4; ++i) {
        int t = t0 + ty + i * 8;
        int c = c0 + tx;
        if (t < 130) xT[((size_t)t * 1024 + b) * 256 + c] = f2b(tile[tx][ty + i * 8]);
    }
}

// ---------------- weight transpose: w (K,N) f32 -> wt (N,K) bf16
__global__ void k_wt(const float* __restrict__ w, unsigned short* __restrict__ wt, int K, int N) {
    __shared__ float tile[32][33];
    int n0 = blockIdx.x * 32, k0 = blockIdx.y * 32;
    int tx = threadIdx.x, ty = threadIdx.y;
#pragma unroll
    for (int i = 0; i < 4; ++i)
        tile[ty + i * 8][tx] = w[(size_t)(k0 + ty + i * 8) * N + n0 + tx];  // [k_local][n_local]
    __syncthreads();
#pragma unroll
    for (int i = 0; i < 4; ++i)
        wt[(size_t)(n0 + ty + i * 8) * K + k0 + tx] = f2b(tile[tx][ty + i * 8]);
}

// ---------------- GEMM (used only for the output projection now)
#define BM 128
#define BN 128
#define BKg 64

template <int MODE, int F32OUT, int BIAS>
__global__ __launch_bounds__(256) void kgemm(const unsigned short* __restrict__ A,
                                             const unsigned short* __restrict__ Wt,
                                             void* __restrict__ Cout,
                                             const float* __restrict__ bias,
                                             int Mtiles, int Ntiles, int KT, int strideA,
                                             int strideB, int N, int tbase) {
    __shared__ unsigned short As[BM * BKg];
    __shared__ unsigned short Bs[BN * BKg];

    int nwg = Mtiles * Ntiles;
    int q = nwg >> 3;
    int orig = blockIdx.x;
    int wg = (orig & 7) * q + (orig >> 3);  // bijective XCD swizzle (nwg%8==0)
    int tn = wg % Ntiles, tm = wg / Ntiles;

    int tid = threadIdx.x;
    int wid = tid >> 6, lane = tid & 63;
    int srow = lane >> 3, skb = lane & 7;
    int lh = lane & 15, lq = lane >> 4;

    f32x4 acc[4][4] = {};
    int m0 = tm * BM;
    int t0 = m0 >> 10, b0 = m0 & 1023;
    int wr = wid >> 1, wc = wid & 1;

    for (int k0 = 0; k0 < KT; k0 += BKg) {
        const unsigned short* Abase;
        int rs;
        if (MODE == 1) {
            int w = k0 >> 8, c0 = k0 & 255;
            Abase = A + ((size_t)((tbase + t0 + w) * 1024 + b0)) * 256 + c0;
            rs = 256;
        } else {
            Abase = A + (size_t)m0 * strideA + k0;
            rs = strideA;
        }
        const unsigned short* Bbase = Wt + (size_t)(tn * BN) * strideB + k0;
#pragma unroll
        for (int c = 0; c < 4; ++c) {
            int chunk = c * 4 + wid;
            int row = chunk * 8 + srow;
            int kbs = skb ^ (row & 7);
            gload_lds16(Abase + (size_t)row * rs + kbs * 8, &As[chunk * 512]);
        }
#pragma unroll
        for (int c = 0; c < 4; ++c) {
            int chunk = c * 4 + wid;
            int row = chunk * 8 + srow;
            int kbs = skb ^ (row & 7);
            gload_lds16(Bbase + (size_t)row * strideB + kbs * 8, &Bs[chunk * 512]);
        }
        __syncthreads();
#pragma unroll
        for (int kk = 0; kk < 2; ++kk) {
            bf16x8 af[4], bfv[4];
            int kc = kk * 4 + lq;
#pragma unroll
            for (int i = 0; i < 4; ++i) {
                int m = wr * 64 + i * 16 + lh;
                af[i] = *(const bf16x8*)((const char*)As + m * 128 + ((kc ^ (m & 7)) * 16));
            }
#pragma unroll
            for (int j = 0; j < 4; ++j) {
                int n = wc * 64 + j * 16 + lh;
                bfv[j] = *(const bf16x8*)((const char*)Bs + n * 128 + ((kc ^ (n & 7)) * 16));
            }
#pragma unroll
            for (int i = 0; i < 4; ++i)
#pragma unroll
                for (int j = 0; j < 4; ++j)
                    acc[i][j] = __builtin_amdgcn_mfma_f32_16x16x32_bf16(af[i], bfv[j], acc[i][j], 0, 0, 0);
        }
        __syncthreads();
    }
#pragma unroll
    for (int i = 0; i < 4; ++i) {
#pragma unroll
        for (int j = 0; j < 4; ++j) {
            int colg = tn * BN + wc * 64 + j * 16 + lh;
            float bv = BIAS ? bias[colg] : 0.0f;
#pragma unroll
            for (int r = 0; r < 4; ++r) {
                int rowg = m0 + wr * 64 + i * 16 + lq * 4 + r;
                float v = acc[i][j][r] + bv;
                if (F32OUT)
                    ((float*)Cout)[(size_t)rowg * N + colg] = v;
                else
                    ((unsigned short*)Cout)[(size_t)rowg * N + colg] = f2b(v);
            }
        }
    }
}

// ---- stage x_t (32 rows x KX cols bf16) into LDS, linear dest, source pre-swizzled
// (swizzle: within each 8-slot (128B) group, slot ^= row&7; matches frag-read side)
template <int KX, int WIN>
DEVI void stage_x(const unsigned short* __restrict__ xin, int t, int b0,
                  unsigned short* xbuf, int tid) {
    constexpr int CH = KX / 16;  // 1KB wave-chunks
    int wid = tid >> 6, lane = tid & 63;
#pragma unroll
    for (int c = wid; c < CH; c += 8) {
        int e = c * 512 + lane * 8;      // element index in [32][KX] tile
        int row = e / KX;                // compile-time divisor
        int slot = (e - row * KX) >> 3;  // 16B slot within row
        int ss = (slot & ~7) | ((slot & 7) ^ (row & 7));
        int col = ss << 3;
        const unsigned short* src;
        if (WIN) {  // window mode: xT (130,1024,256), K = [w=0|w=1|w=2] x 256
            int w = col >> 8, cc = col & 255;
            src = xin + ((size_t)((t + w) * 1024 + b0 + row)) * 256 + cc;
        } else {
            src = xin + ((size_t)t * 1024 + b0 + row) * (size_t)KX + col;
        }
        gload_lds16(src, xbuf + c * 512);
    }
}

// ---------------- fused LSTM layer: gates = [x_t | h] @ W^T + b, all 128 steps, one dispatch.
// 64 blocks (xcd-split by dir), 512 threads (8 waves), 32 batch rows/block.
// h in swizzled LDS; x_t double-buffer prefetched into swizzled LDS; W streamed from L2.
template <int KX, int WIN>
__global__ __launch_bounds__(512) void klstm_f(const unsigned short* __restrict__ xin,
                                               const unsigned short* __restrict__ wtf,
                                               const unsigned short* __restrict__ wtb,
                                               const float* __restrict__ bf_,
                                               const float* __restrict__ bb_,
                                               unsigned short* __restrict__ xs_out) {
    constexpr int KS = KX + 256;   // total K (x-part + h-part)
    constexpr int KF_X = KX / 32;  // x-part MFMA k-steps
    __shared__ unsigned short h_lds[32 * 256];     // 16 KB, XOR-swizzled
    __shared__ unsigned short xb[2][32 * KX];      // 2 x (48 or 32 KB)

    int bid = blockIdx.x;
    int xcd = bid & 7;
    int dir = xcd >> 2;                       // XCDs 0-3: fw, 4-7: bw (one dir's W per XCD L2)
    int idx = (bid >> 3) * 4 + (xcd & 3);     // [0,32)
    int b0 = idx * 32;
    const unsigned short* wt = dir ? wtb : wtf;  // (1024 gates, KS) bf16
    const float* bias = dir ? bb_ : bf_;

    int tid = threadIdx.x, wid = tid >> 6, lane = tid & 63;
    int lh = lane & 15, lq = lane >> 4;

    for (int i = tid; i < 32 * 256; i += 512) h_lds[i] = 0;

    float c_reg[2][2][4] = {};
    float bia[2], big[2], bif[2], bio[2];
#pragma unroll
    for (int p = 0; p < 2; ++p) {
        int col = wid * 32 + p * 16 + lh;
        bia[p] = bias[col];
        big[p] = bias[256 + col];
        bif[p] = bias[512 + col];
        bio[p] = bias[768 + col];
    }
    stage_x<KX, WIN>(xin, dir ? 127 : 0, b0, &xb[0][0], tid);
    __syncthreads();  // implicit vmcnt(0): prologue stage + h zero-init done

    for (int s = 0; s < 128; ++s) {
        int t = dir ? (127 - s) : s;
        int tnx = dir ? (t > 0 ? t - 1 : 0) : (t < 127 ? t + 1 : 127);
        const unsigned short* xcur = &xb[s & 1][0];

        // prefetch next step's x (drained by the end-of-step barrier's vmcnt(0))
        stage_x<KX, WIN>(xin, tnx, b0, &xb[(s & 1) ^ 1][0], tid);

        f32x4 acc[2][8] = {};
        // x-part: A from xb[cur]
#pragma unroll 4
        for (int kf = 0; kf < KF_X; ++kf) {
            int kc = kf * 4 + lq;
            bf16x8 a0, a1;
            {
                int m = lh;
                int ss = (kc & ~7) | ((kc & 7) ^ (m & 7));
                a0 = *(const bf16x8*)((const char*)xcur + m * (KX * 2) + ss * 16);
            }
            {
                int m = 16 + lh;
                int ss = (kc & ~7) | ((kc & 7) ^ (m & 7));
                a1 = *(const bf16x8*)((const char*)xcur + m * (KX * 2) + ss * 16);
            }
#pragma unroll
            for (int nf = 0; nf < 8; ++nf) {
                int g = nf >> 1, p = nf & 1;
                int n = g * 256 + wid * 32 + p * 16 + lh;
                bf16x8 bfr = *(const bf16x8*)(wt + (size_t)n * KS + kf * 32 + lq * 8);
                acc[0][nf] = __builtin_amdgcn_mfma_f32_16x16x32_bf16(a0, bfr, acc[0][nf], 0, 0, 0);
                acc[1][nf] = __builtin_amdgcn_mfma_f32_16x16x32_bf16(a1, bfr, acc[1][nf], 0, 0, 0);
            }
        }
        // h-part: A from h_lds
#pragma unroll
        for (int kf = 0; kf < 8; ++kf) {
            int kc = kf * 4 + lq;
            bf16x8 a0, a1;
            {
                int m = lh;
                a0 = *(const bf16x8*)((const char*)h_lds + m * 512 + ((kc ^ (m & 7)) * 16));
            }
            {
                int m = 16 + lh;
                a1 = *(const bf16x8*)((const char*)h_lds + m * 512 + ((kc ^ (m & 7)) * 16));
            }
#pragma unroll
            for (int nf = 0; nf < 8; ++nf) {
                int g = nf >> 1, p = nf & 1;
                int n = g * 256 + wid * 32 + p * 16 + lh;
                bf16x8 bfr = *(const bf16x8*)(wt + (size_t)n * KS + KX + kf * 32 + lq * 8);
                acc[0][nf] = __builtin_amdgcn_mfma_f32_16x16x32_bf16(a0, bfr, acc[0][nf], 0, 0, 0);
                acc[1][nf] = __builtin_amdgcn_mfma_f32_16x16x32_bf16(a1, bfr, acc[1][nf], 0, 0, 0);
            }
        }
        __syncthreads();  // (C) all waves' h reads complete before h writes

        // elementwise LSTM update (each lane owns 16 (row,col) cells)
#pragma unroll
        for (int mf = 0; mf < 2; ++mf) {
#pragma unroll
            for (int r = 0; r < 4; ++r) {
                int row = mf * 16 + lq * 4 + r;
#pragma unroll
                for (int p = 0; p < 2; ++p) {
                    int col = wid * 32 + p * 16 + lh;
                    float gi = acc[mf][0 + p][r] + bia[p];
                    float gg = acc[mf][2 + p][r] + big[p];
                    float gf = acc[mf][4 + p][r] + bif[p];
                    float go = acc[mf][6 + p][r] + bio[p];
                    float cv = sigm(gf + 1.0f) * c_reg[mf][p][r] + sigm(gi) * tanh_f(gg);
                    c_reg[mf][p][r] = cv;
                    float hv = sigm(go) * tanh_f(cv);
                    unsigned short hb = f2b(hv);
                    *(unsigned short*)((char*)h_lds + row * 512 + (((col >> 3) ^ (row & 7)) * 16) +
                                       (col & 7) * 2) = hb;
                    xs_out[((size_t)t * 1024 + b0 + row) * 512 + dir * 256 + col] = hb;
                }
            }
        }
        __syncthreads();  // (A) h writes visible; implicit vmcnt(0) drains x prefetch
    }
}

// ---------------- output transpose: tmp (L,B,O) f32 -> out (B,O,L) f32
__global__ void k_tout(const float* __restrict__ tmp, float* __restrict__ out) {
    __shared__ float tile[32][33];
    int o0 = blockIdx.x * 32, l0 = blockIdx.y * 32, b = blockIdx.z;
    int tx = threadIdx.x, ty = threadIdx.y;
#pragma unroll
    for (int i = 0; i < 4; ++i)
        tile[ty + i * 8][tx] = tmp[((size_t)(l0 + ty + i * 8) * 1024 + b) * 256 + o0 + tx];
    __syncthreads();
#pragma unroll
    for (int i = 0; i < 4; ++i)
        out[((size_t)b * 256 + o0 + ty + i * 8) * 128 + l0 + tx] = tile[tx][ty + i * 8];
}

extern "C" void kernel_launch(void* const* d_in, const int* in_sizes, int n_in,
                              void* d_out, int out_size, void* d_ws, size_t ws_size,
                              hipStream_t stream) {
    const float* inp  = (const float*)d_in[0];
    const float* wfw0 = (const float*)d_in[1];
    const float* bfw0 = (const float*)d_in[2];
    const float* wbw0 = (const float*)d_in[3];
    const float* bbw0 = (const float*)d_in[4];
    const float* wfwr = (const float*)d_in[5];
    const float* bfwr = (const float*)d_in[6];
    const float* wbwr = (const float*)d_in[7];
    const float* bbwr = (const float*)d_in[8];
    const float* wout = (const float*)d_in[9];
    const float* bout = (const float*)d_in[10];

    char* ws = (char*)d_ws;
    size_t o = 0;
    auto alloc = [&](size_t bytes) {
        void* p = ws + o;
        o += (bytes + 255) & ~(size_t)255;
        return p;
    };
    unsigned short* wt0f = (unsigned short*)alloc((size_t)1024 * 1024 * 2);
    unsigned short* wt0b = (unsigned short*)alloc((size_t)1024 * 1024 * 2);
    unsigned short* wt1f = (unsigned short*)alloc((size_t)1024 * 768 * 2);
    unsigned short* wt1b = (unsigned short*)alloc((size_t)1024 * 768 * 2);
    unsigned short* wt2f = (unsigned short*)alloc((size_t)1024 * 768 * 2);
    unsigned short* wt2b = (unsigned short*)alloc((size_t)1024 * 768 * 2);
    unsigned short* wto  = (unsigned short*)alloc((size_t)256 * 512 * 2);
    unsigned short* xsa  = (unsigned short*)alloc((size_t)131072 * 512 * 2);
    unsigned short* xsbR = (unsigned short*)alloc((size_t)131072 * 512 * 2);
    // lifetime-disjoint aliases of xsbR's 134MB region:
    unsigned short* xT   = xsbR;          // layer-0 input (dead once layer 1 writes xsbR)
    float*          otmp = (float*)xsbR;  // out-proj temp (xsbR dead after layer-2 read)

    dim3 tb(32, 8);
    k_tin<<<dim3(8, 5, 1024), tb, 0, stream>>>(inp, xT);
    k_wt<<<dim3(32, 32), tb, 0, stream>>>(wfw0, wt0f, 1024, 1024);
    k_wt<<<dim3(32, 32), tb, 0, stream>>>(wbw0, wt0b, 1024, 1024);
    k_wt<<<dim3(32, 24), tb, 0, stream>>>(wfwr, wt1f, 768, 1024);
    k_wt<<<dim3(32, 24), tb, 0, stream>>>(wbwr, wt1b, 768, 1024);
    k_wt<<<dim3(32, 24), tb, 0, stream>>>(wfwr + (size_t)768 * 1024, wt2f, 768, 1024);
    k_wt<<<dim3(32, 24), tb, 0, stream>>>(wbwr + (size_t)768 * 1024, wt2b, 768, 1024);
    k_wt<<<dim3(8, 16), tb, 0, stream>>>(wout, wto, 512, 256);

    // fused BiLSTM layers (one dispatch each)
    klstm_f<768, 1><<<64, 512, 0, stream>>>(xT, wt0f, wt0b, bfw0, bbw0, xsa);
    klstm_f<512, 0><<<64, 512, 0, stream>>>(xsa, wt1f, wt1b, bfwr, bbwr, xsbR);
    klstm_f<512, 0><<<64, 512, 0, stream>>>(xsbR, wt2f, wt2b, bfwr + 1024, bbwr + 1024, xsa);

    // output projection (f32 + bias) then transpose to (B,O,L)
    kgemm<0, 1, 1><<<2048, 256, 0, stream>>>(xsa, wto, otmp, bout, 1024, 2, 512, 512, 512, 256, 0);
    k_tout<<<dim3(8, 4, 1024), tb, 0, stream>>>(otmp, (float*)d_out);
}

// Round 4
// 8663.029 us; speedup vs baseline: 2.6188x; 2.6188x over previous
//
#include <hip/hip_runtime.h>
#include <cstdint>

#define DEVI __device__ __forceinline__

typedef __bf16 bf16x8 __attribute__((ext_vector_type(8)));
typedef float f32x4 __attribute__((ext_vector_type(4)));

DEVI unsigned short f2b(float f) {
    unsigned int u = __builtin_bit_cast(unsigned int, f);
    unsigned int r = (u + 0x7FFFu + ((u >> 16) & 1u)) >> 16;
    return (unsigned short)r;
}
DEVI float b2f(unsigned short h) {
    unsigned int u = ((unsigned int)h) << 16;
    return __builtin_bit_cast(float, u);
}
DEVI float frcp(float x) { return __builtin_amdgcn_rcpf(x); }
DEVI float sigm(float x) { return frcp(1.0f + __expf(-x)); }
DEVI float tanh_f(float x) {
    float e = __expf(-2.0f * fabsf(x));
    float r = (1.0f - e) * frcp(1.0f + e);
    return x < 0.0f ? -r : r;
}

// async global->LDS, 16B per lane; LDS dest wave-uniform base (HW adds lane*16).
DEVI void gload_lds16(const unsigned short* g, unsigned short* l) {
    typedef __attribute__((address_space(1))) void gv_t;
    typedef __attribute__((address_space(3))) void lv_t;
    gv_t* gp = (gv_t*)(uintptr_t)g;
    lv_t* lp = (lv_t*)(unsigned int)(uintptr_t)l;
    __builtin_amdgcn_global_load_lds(gp, lp, 16, 0, 0);
}

// ---------------- input transpose: (B,C,L) f32 -> xT (L+2, B, C) bf16, zero rows 0 and 129
__global__ void k_tin(const float* __restrict__ in, unsigned short* __restrict__ xT) {
    __shared__ float tile[32][33];
    int c0 = blockIdx.x * 32, t0 = blockIdx.y * 32, b = blockIdx.z;
    int tx = threadIdx.x, ty = threadIdx.y;
#pragma unroll
    for (int i = 0; i < 4; ++i) {
        int c = c0 + ty + i * 8;
        int t = t0 + tx;
        float v = 0.0f;
        if (t >= 1 && t <= 128) v = in[((size_t)b * 256 + c) * 128 + (t - 1)];
        tile[ty + i * 8][tx] = v;  // [c_local][t_local]
    }
    __syncthreads();
#pragma unroll
    for (int i = 0; i < 4; ++i) {
        int t = t0 + ty + i * 8;
        int c = c0 + tx;
        if (t < 130) xT[((size_t)t * 1024 + b) * 256 + c] = f2b(tile[tx][ty + i * 8]);
    }
}

// ---------------- weight transpose: w (K,N) f32 -> wt (N,K) bf16
__global__ void k_wt(const float* __restrict__ w, unsigned short* __restrict__ wt, int K, int N) {
    __shared__ float tile[32][33];
    int n0 = blockIdx.x * 32, k0 = blockIdx.y * 32;
    int tx = threadIdx.x, ty = threadIdx.y;
#pragma unroll
    for (int i = 0; i < 4; ++i)
        tile[ty + i * 8][tx] = w[(size_t)(k0 + ty + i * 8) * N + n0 + tx];  // [k_local][n_local]
    __syncthreads();
#pragma unroll
    for (int i = 0; i < 4; ++i)
        wt[(size_t)(n0 + ty + i * 8) * K + k0 + tx] = f2b(tile[tx][ty + i * 8]);
}

// ---------------- GEMM: C[M,N] = A[M,K] @ Wt[N,K]^T   (bf16 in, f32 acc)
// MODE 0: A row-major (strideA). MODE 1: layer-0 window mode, A = xT (130,1024,256), t += tbase.
#define BM 128
#define BN 128
#define BKg 64

template <int MODE, int F32OUT, int BIAS>
__global__ __launch_bounds__(256) void kgemm(const unsigned short* __restrict__ A,
                                             const unsigned short* __restrict__ Wt,
                                             void* __restrict__ Cout,
                                             const float* __restrict__ bias,
                                             int Mtiles, int Ntiles, int KT, int strideA,
                                             int strideB, int N, int tbase) {
    __shared__ unsigned short As[BM * BKg];
    __shared__ unsigned short Bs[BN * BKg];

    int nwg = Mtiles * Ntiles;
    int q = nwg >> 3;
    int orig = blockIdx.x;
    int wg = (orig & 7) * q + (orig >> 3);  // bijective XCD swizzle (nwg%8==0)
    int tn = wg % Ntiles, tm = wg / Ntiles;

    int tid = threadIdx.x;
    int wid = tid >> 6, lane = tid & 63;
    int srow = lane >> 3, skb = lane & 7;
    int lh = lane & 15, lq = lane >> 4;

    f32x4 acc[4][4] = {};
    int m0 = tm * BM;
    int t0 = m0 >> 10, b0 = m0 & 1023;
    int wr = wid >> 1, wc = wid & 1;

    for (int k0 = 0; k0 < KT; k0 += BKg) {
        const unsigned short* Abase;
        int rs;
        if (MODE == 1) {
            int w = k0 >> 8, c0 = k0 & 255;
            Abase = A + ((size_t)((tbase + t0 + w) * 1024 + b0)) * 256 + c0;
            rs = 256;
        } else {
            Abase = A + (size_t)m0 * strideA + k0;
            rs = strideA;
        }
        const unsigned short* Bbase = Wt + (size_t)(tn * BN) * strideB + k0;
#pragma unroll
        for (int c = 0; c < 4; ++c) {
            int chunk = c * 4 + wid;
            int row = chunk * 8 + srow;
            int kbs = skb ^ (row & 7);
            gload_lds16(Abase + (size_t)row * rs + kbs * 8, &As[chunk * 512]);
        }
#pragma unroll
        for (int c = 0; c < 4; ++c) {
            int chunk = c * 4 + wid;
            int row = chunk * 8 + srow;
            int kbs = skb ^ (row & 7);
            gload_lds16(Bbase + (size_t)row * strideB + kbs * 8, &Bs[chunk * 512]);
        }
        __syncthreads();
#pragma unroll
        for (int kk = 0; kk < 2; ++kk) {
            bf16x8 af[4], bfv[4];
            int kc = kk * 4 + lq;
#pragma unroll
            for (int i = 0; i < 4; ++i) {
                int m = wr * 64 + i * 16 + lh;
                af[i] = *(const bf16x8*)((const char*)As + m * 128 + ((kc ^ (m & 7)) * 16));
            }
#pragma unroll
            for (int j = 0; j < 4; ++j) {
                int n = wc * 64 + j * 16 + lh;
                bfv[j] = *(const bf16x8*)((const char*)Bs + n * 128 + ((kc ^ (n & 7)) * 16));
            }
#pragma unroll
            for (int i = 0; i < 4; ++i)
#pragma unroll
                for (int j = 0; j < 4; ++j)
                    acc[i][j] = __builtin_amdgcn_mfma_f32_16x16x32_bf16(af[i], bfv[j], acc[i][j], 0, 0, 0);
        }
        __syncthreads();
    }
#pragma unroll
    for (int i = 0; i < 4; ++i) {
#pragma unroll
        for (int j = 0; j < 4; ++j) {
            int colg = tn * BN + wc * 64 + j * 16 + lh;
            float bv = BIAS ? bias[colg] : 0.0f;
#pragma unroll
            for (int r = 0; r < 4; ++r) {
                int rowg = m0 + wr * 64 + i * 16 + lq * 4 + r;
                float v = acc[i][j][r] + bv;
                if (F32OUT)
                    ((float*)Cout)[(size_t)rowg * N + colg] = v;
                else
                    ((unsigned short*)Cout)[(size_t)rowg * N + colg] = f2b(v);
            }
        }
    }
}

// ---------------- recurrent LSTM phase, chunked [s0, s0+Tc), software-pipelined W loads.
// grid (32 row-blocks, 2 dirs), 512 threads (8 waves). Block owns 32 batch rows.
// wth: (2048, 256) bf16 — fw gate rows [0,1024), bw [1024,2048), row stride 256.
__global__ __launch_bounds__(512, 2) void klstm_p(const unsigned short* __restrict__ gxf,
                                                  const unsigned short* __restrict__ gxb, int GS,
                                                  const unsigned short* __restrict__ wth,
                                                  const float* __restrict__ bf_,
                                                  const float* __restrict__ bb_,
                                                  unsigned short* __restrict__ xs_out,
                                                  unsigned short* __restrict__ hst,
                                                  float* __restrict__ cst, int s0, int Tc) {
    __shared__ unsigned short h_lds[32 * 256];  // [row][col] bf16, XOR-swizzled, 16KB
    int dir = blockIdx.y;
    int b0 = blockIdx.x * 32;
    const unsigned short* gx = dir ? gxb : gxf;
    const unsigned short* wh = wth + (size_t)dir * 1024 * 256;
    const float* bias = dir ? bb_ : bf_;

    int tid = threadIdx.x, wid = tid >> 6, lane = tid & 63;
    int lh = lane & 15, lq = lane >> 4;

    float c_reg[2][2][4] = {};
    if (s0 == 0) {
        for (int i = tid; i < 32 * 256; i += 512) h_lds[i] = 0;
    } else {
        for (int i = tid; i < 32 * 256; i += 512) {
            int row = i >> 8, col = i & 255;
            *(unsigned short*)((char*)h_lds + row * 512 + (((col >> 3) ^ (row & 7)) * 16) +
                               (col & 7) * 2) = hst[((size_t)dir * 1024 + b0 + row) * 256 + col];
        }
#pragma unroll
        for (int mf = 0; mf < 2; ++mf)
#pragma unroll
            for (int r = 0; r < 4; ++r)
#pragma unroll
                for (int p = 0; p < 2; ++p) {
                    int row = mf * 16 + lq * 4 + r;
                    int col = wid * 32 + p * 16 + lh;
                    c_reg[mf][p][r] = cst[((size_t)dir * 1024 + b0 + row) * 256 + col];
                }
    }
    float bia[2], big[2], bif[2], bio[2];
#pragma unroll
    for (int p = 0; p < 2; ++p) {
        int col = wid * 32 + p * 16 + lh;
        bia[p] = bias[col];
        big[p] = bias[256 + col];
        bif[p] = bias[512 + col];
        bio[p] = bias[768 + col];
    }
    // per-wave W row base pointers (8 nf slices)
    const unsigned short* wb[8];
#pragma unroll
    for (int nf = 0; nf < 8; ++nf) {
        int g = nf >> 1, p = nf & 1;
        int n = g * 256 + wid * 32 + p * 16 + lh;
        wb[nf] = wh + (size_t)n * 256 + lq * 8;
    }
    __syncthreads();

    for (int s = s0; s < s0 + Tc; ++s) {
        int t = dir ? (127 - s) : s;
        int gloc = dir ? (s0 + Tc - 1 - s) : (s - s0);

        f32x4 acc[2][8] = {};
        bf16x8 wreg[3][8];  // rotating depth-3 W pipeline (static idx under unroll)
        bf16x8 afr[2][2];   // depth-2 h-fragment pipeline

#define LDW(KF, SLOT)                                                       \
    {                                                                       \
        _Pragma("unroll") for (int nf = 0; nf < 8; ++nf) wreg[SLOT][nf] =   \
            *(const bf16x8*)(wb[nf] + (KF)*32);                             \
    }
#define LDA(KF, SLOT)                                                        \
    {                                                                        \
        int kc = (KF)*4 + lq;                                                \
        _Pragma("unroll") for (int mf = 0; mf < 2; ++mf) {                   \
            int m = mf * 16 + lh;                                            \
            afr[SLOT][mf] = *(const bf16x8*)((const char*)h_lds + m * 512 +  \
                                             ((kc ^ (m & 7)) * 16));         \
        }                                                                    \
    }
        LDW(0, 0);
        LDW(1, 1);
        LDA(0, 0);
#pragma unroll
        for (int kf = 0; kf < 8; ++kf) {
            if (kf < 6) LDW(kf + 2, (kf + 2) % 3);
            if (kf < 7) LDA(kf + 1, (kf + 1) & 1);
#pragma unroll
            for (int nf = 0; nf < 8; ++nf) {
                acc[0][nf] = __builtin_amdgcn_mfma_f32_16x16x32_bf16(afr[kf & 1][0], wreg[kf % 3][nf],
                                                                    acc[0][nf], 0, 0, 0);
                acc[1][nf] = __builtin_amdgcn_mfma_f32_16x16x32_bf16(afr[kf & 1][1], wreg[kf % 3][nf],
                                                                    acc[1][nf], 0, 0, 0);
            }
        }
#undef LDW
#undef LDA
        __syncthreads();  // (1) all h reads complete before h writes

        // batched gx loads: 64 independent u16 loads, single wait
        unsigned short gu[2][2][4][4];  // [mf][p][r][gate]
#pragma unroll
        for (int mf = 0; mf < 2; ++mf)
#pragma unroll
            for (int r = 0; r < 4; ++r) {
                int row = mf * 16 + lq * 4 + r;
                const unsigned short* gp = gx + ((size_t)gloc * 1024 + b0 + row) * GS;
#pragma unroll
                for (int p = 0; p < 2; ++p) {
                    int col = wid * 32 + p * 16 + lh;
#pragma unroll
                    for (int g = 0; g < 4; ++g) gu[mf][p][r][g] = gp[g * 256 + col];
                }
            }
#pragma unroll
        for (int mf = 0; mf < 2; ++mf) {
#pragma unroll
            for (int r = 0; r < 4; ++r) {
                int row = mf * 16 + lq * 4 + r;
#pragma unroll
                for (int p = 0; p < 2; ++p) {
                    int col = wid * 32 + p * 16 + lh;
                    float gi = acc[mf][0 + p][r] + b2f(gu[mf][p][r][0]) + bia[p];
                    float gg = acc[mf][2 + p][r] + b2f(gu[mf][p][r][1]) + big[p];
                    float gf = acc[mf][4 + p][r] + b2f(gu[mf][p][r][2]) + bif[p];
                    float go = acc[mf][6 + p][r] + b2f(gu[mf][p][r][3]) + bio[p];
                    float cv = sigm(gf + 1.0f) * c_reg[mf][p][r] + sigm(gi) * tanh_f(gg);
                    c_reg[mf][p][r] = cv;
                    float hv = sigm(go) * tanh_f(cv);
                    unsigned short hb = f2b(hv);
                    *(unsigned short*)((char*)h_lds + row * 512 + (((col >> 3) ^ (row & 7)) * 16) +
                                       (col & 7) * 2) = hb;
                    xs_out[((size_t)t * 1024 + b0 + row) * 512 + dir * 256 + col] = hb;
                }
            }
        }
        __syncthreads();  // (2) h writes visible for next step
    }

    // carry state out (only meaningful when chunked; cheap)
    for (int i = tid; i < 32 * 256; i += 512) {
        int row = i >> 8, col = i & 255;
        hst[((size_t)dir * 1024 + b0 + row) * 256 + col] =
            *(const unsigned short*)((const char*)h_lds + row * 512 +
                                     (((col >> 3) ^ (row & 7)) * 16) + (col & 7) * 2);
    }
#pragma unroll
    for (int mf = 0; mf < 2; ++mf)
#pragma unroll
        for (int r = 0; r < 4; ++r)
#pragma unroll
            for (int p = 0; p < 2; ++p) {
                int row = mf * 16 + lq * 4 + r;
                int col = wid * 32 + p * 16 + lh;
                cst[((size_t)dir * 1024 + b0 + row) * 256 + col] = c_reg[mf][p][r];
            }
}

// ---------------- output transpose: tmp (L,B,O) f32 -> out (B,O,L) f32
__global__ void k_tout(const float* __restrict__ tmp, float* __restrict__ out) {
    __shared__ float tile[32][33];
    int o0 = blockIdx.x * 32, l0 = blockIdx.y * 32, b = blockIdx.z;
    int tx = threadIdx.x, ty = threadIdx.y;
#pragma unroll
    for (int i = 0; i < 4; ++i)
        tile[ty + i * 8][tx] = tmp[((size_t)(l0 + ty + i * 8) * 1024 + b) * 256 + o0 + tx];
    __syncthreads();
#pragma unroll
    for (int i = 0; i < 4; ++i)
        out[((size_t)b * 256 + o0 + ty + i * 8) * 128 + l0 + tx] = tile[tx][ty + i * 8];
}

extern "C" void kernel_launch(void* const* d_in, const int* in_sizes, int n_in,
                              void* d_out, int out_size, void* d_ws, size_t ws_size,
                              hipStream_t stream) {
    const float* inp  = (const float*)d_in[0];
    const float* wfw0 = (const float*)d_in[1];
    const float* bfw0 = (const float*)d_in[2];
    const float* wbw0 = (const float*)d_in[3];
    const float* bbw0 = (const float*)d_in[4];
    const float* wfwr = (const float*)d_in[5];
    const float* bfwr = (const float*)d_in[6];
    const float* wbwr = (const float*)d_in[7];
    const float* bbwr = (const float*)d_in[8];
    const float* wout = (const float*)d_in[9];
    const float* bout = (const float*)d_in[10];

    char* ws = (char*)d_ws;
    size_t o = 0;
    auto alloc = [&](size_t bytes) {
        void* p = ws + o;
        o += (bytes + 255) & ~(size_t)255;
        return p;
    };
    // packed x-part weights (2048, KX): fw rows [0,1024), bw [1024,2048)
    unsigned short* wtx0 = (unsigned short*)alloc((size_t)2048 * 768 * 2);
    unsigned short* wtx1 = (unsigned short*)alloc((size_t)2048 * 512 * 2);
    unsigned short* wtx2 = (unsigned short*)alloc((size_t)2048 * 512 * 2);
    // h-part weights (2048, 256), dense row stride 256
    unsigned short* wth0 = (unsigned short*)alloc((size_t)2048 * 256 * 2);
    unsigned short* wth1 = (unsigned short*)alloc((size_t)2048 * 256 * 2);
    unsigned short* wth2 = (unsigned short*)alloc((size_t)2048 * 256 * 2);
    unsigned short* wto  = (unsigned short*)alloc((size_t)256 * 512 * 2);
    unsigned short* hst  = (unsigned short*)alloc((size_t)2 * 1024 * 256 * 2);
    float*          cst  = (float*)alloc((size_t)2 * 1024 * 256 * 4);
    unsigned short* xsa  = (unsigned short*)alloc((size_t)131072 * 512 * 2);
    unsigned short* xsbR = (unsigned short*)alloc((size_t)131072 * 512 * 2);
    unsigned short* xT   = xsbR;          // alias: layer-0 input staging
    float*          otmp = (float*)xsbR;  // alias: out-proj temp

    // gate buffer: fused needs 128*1024*2048*2 = 537MB; chunked path uses same formula
    size_t base = o;
    int Tc = 128;
    while (Tc > 1 && base + (size_t)Tc * 1024 * 2048 * 2 > ws_size) Tc >>= 1;
    bool fused = (Tc == 128);
    unsigned short* gx  = (unsigned short*)alloc((size_t)Tc * 1024 * 2048 * 2);
    unsigned short* gxB = gx + (size_t)Tc * 1024 * 1024;  // chunked: bw half

    dim3 tb(32, 8);
    k_tin<<<dim3(8, 5, 1024), tb, 0, stream>>>(inp, xT);
    // layer 0 weights: w (1024, 1024): x rows [0,768), h rows [768,1024)
    k_wt<<<dim3(32, 24), tb, 0, stream>>>(wfw0, wtx0, 768, 1024);
    k_wt<<<dim3(32, 24), tb, 0, stream>>>(wbw0, wtx0 + (size_t)1024 * 768, 768, 1024);
    k_wt<<<dim3(32, 8), tb, 0, stream>>>(wfw0 + (size_t)768 * 1024, wth0, 256, 1024);
    k_wt<<<dim3(32, 8), tb, 0, stream>>>(wbw0 + (size_t)768 * 1024, wth0 + (size_t)1024 * 256, 256, 1024);
    // layers 1,2: w_rest (2, 768, 1024): x rows [0,512), h rows [512,768)
    for (int k = 0; k < 2; ++k) {
        unsigned short* wtx = k ? wtx2 : wtx1;
        unsigned short* wth_ = k ? wth2 : wth1;
        const float* wf = wfwr + (size_t)k * 768 * 1024;
        const float* wbk = wbwr + (size_t)k * 768 * 1024;
        k_wt<<<dim3(32, 16), tb, 0, stream>>>(wf, wtx, 512, 1024);
        k_wt<<<dim3(32, 16), tb, 0, stream>>>(wbk, wtx + (size_t)1024 * 512, 512, 1024);
        k_wt<<<dim3(32, 8), tb, 0, stream>>>(wf + (size_t)512 * 1024, wth_, 256, 1024);
        k_wt<<<dim3(32, 8), tb, 0, stream>>>(wbk + (size_t)512 * 1024, wth_ + (size_t)1024 * 256, 256, 1024);
    }
    k_wt<<<dim3(8, 16), tb, 0, stream>>>(wout, wto, 512, 256);

    auto layer = [&](const unsigned short* xin, int KX, bool win, unsigned short* wtx,
                     unsigned short* wth_, const float* bfp, const float* bbp,
                     unsigned short* xout) {
        if (fused) {
            if (win)
                kgemm<1, 0, 0><<<16384, 256, 0, stream>>>(xin, wtx, gx, nullptr, 1024, 16, KX, 256, KX, 2048, 0);
            else
                kgemm<0, 0, 0><<<16384, 256, 0, stream>>>(xin, wtx, gx, nullptr, 1024, 16, KX, KX, KX, 2048, 0);
            klstm_p<<<dim3(32, 2), 512, 0, stream>>>(gx, gx + 1024, 2048, wth_, bfp, bbp, xout, hst, cst, 0, 128);
        } else {
            for (int s0 = 0; s0 < 128; s0 += Tc) {
                int tbw = 128 - s0 - Tc;
                if (win) {
                    kgemm<1, 0, 0><<<Tc * 64, 256, 0, stream>>>(xin, wtx, gx, nullptr, Tc * 8, 8, KX, 256, KX, 1024, s0);
                    kgemm<1, 0, 0><<<Tc * 64, 256, 0, stream>>>(xin, wtx + (size_t)1024 * KX, gxB, nullptr, Tc * 8, 8, KX, 256, KX, 1024, tbw);
                } else {
                    kgemm<0, 0, 0><<<Tc * 64, 256, 0, stream>>>(xin + (size_t)s0 * 1024 * KX, wtx, gx, nullptr, Tc * 8, 8, KX, KX, KX, 1024, 0);
                    kgemm<0, 0, 0><<<Tc * 64, 256, 0, stream>>>(xin + (size_t)tbw * 1024 * KX, wtx + (size_t)1024 * KX, gxB, nullptr, Tc * 8, 8, KX, KX, KX, 1024, 0);
                }
                klstm_p<<<dim3(32, 2), 512, 0, stream>>>(gx, gxB, 1024, wth_, bfp, bbp, xout, hst, cst, s0, Tc);
            }
        }
    };

    layer(xT, 768, true, wtx0, wth0, bfw0, bbw0, xsa);
    layer(xsa, 512, false, wtx1, wth1, bfwr, bbwr, xsbR);
    layer(xsbR, 512, false, wtx2, wth2, bfwr + 1024, bbwr + 1024, xsa);

    // output projection (f32 + bias) then transpose to (B,O,L)
    kgemm<0, 1, 1><<<2048, 256, 0, stream>>>(xsa, wto, otmp, bout, 1024, 2, 512, 512, 512, 256, 0);
    k_tout<<<dim3(8, 4, 1024), tb, 0, stream>>>(otmp, (float*)d_out);
}